// Round 5
// baseline (261.217 us; speedup 1.0000x reference)
//
#include <hip/hip_runtime.h>
#include <hip/hip_bf16.h>

// NLM_7962869366897: fused per-feature GLU-MLP
// B=512, D=2048, M=32, H=64 (2H=128)
// Layer1: per-d [512x32]@[32x128] via mfma_f32_16x16x32_bf16 (K=32 exactly)
// GLU + layer2 [64x2] + GLU in fp32 VALU epilogue.

#define NB 512
#define ND 2048
#define NM 32
#define NH 64

typedef __bf16 bf16x8 __attribute__((ext_vector_type(8)));
typedef float f32x4 __attribute__((ext_vector_type(4)));

#define LDS_STRIDE 40  // 128 rows x 40 shorts (pad 32->40, keeps 16B align, breaks bank conflicts)

__device__ __forceinline__ float sigmoid_fast(float x) {
    // 1/(1+exp(-x)) via exp2; rcp/exp2 are ~1ulp, threshold budget is bf16-scale
    return __builtin_amdgcn_rcpf(1.0f + __builtin_amdgcn_exp2f(-1.442695040888963f * x));
}

__global__ __launch_bounds__(256) void nlm_fused(
    const float* __restrict__ st,   // [B, D, M]
    const float* __restrict__ w1a,  // [M, 2H, D]
    const float* __restrict__ b1a,  // [1, D, 2H]
    const float* __restrict__ Ta,   // [1]
    const float* __restrict__ w1b,  // [H, 2, D]
    const float* __restrict__ b1b,  // [1, D, 2]
    const float* __restrict__ Tb,   // [1]
    float* __restrict__ out)        // [B, D]
{
    __shared__ __bf16 w1_lds[128 * LDS_STRIDE]; // [h][m] bf16, padded
    __shared__ float  w2_lds[128];              // (h*2+c)

    const int bid  = blockIdx.x;
    // XCD-chunked swizzle: each XCD gets 256 consecutive d -> w1a/w1b/out lines
    // (32 consecutive d each) stay within one XCD's L2.
    const int d    = (bid & 7) * (ND / 8) + (bid >> 3);
    const int tid  = threadIdx.x;
    const int wave = tid >> 6;
    const int lane = tid & 63;
    const int l15  = lane & 15;
    const int lg   = lane >> 4;     // 0..3

    // ---- cooperative stage: w1a column d -> LDS as bf16 [h][m] ----
    // w1a linear (m,h) index = m*128+h at global offset idx*ND + d
    {
        const int h    = tid & 127;
        const int half = tid >> 7;           // 0/1 -> m = half*16 + i
        #pragma unroll
        for (int i = 0; i < 16; ++i) {
            const int m = half * 16 + i;
            float v = w1a[(size_t)(m * 128 + h) * ND + d];
            w1_lds[h * LDS_STRIDE + m] = (__bf16)v;
        }
    }
    // ---- w2 (layer-2 weights) column d -> LDS fp32 ----
    if (tid < 128) {
        w2_lds[tid] = w1b[(size_t)tid * ND + d];   // linear (h*2+c)
    }

    const float rTa = 1.0f / Ta[0];
    const float rTb = 1.0f / Tb[0];
    const float bb0 = b1b[d * 2 + 0];
    const float bb1 = b1b[d * 2 + 1];

    // ---- b1a -> regs (used as MFMA C-init): bias[t][r] = b1a[d][t*16+lg*4+r] ----
    f32x4 bias[8];
    #pragma unroll
    for (int t = 0; t < 8; ++t)
        bias[t] = *(const f32x4*)(b1a + (size_t)d * 128 + t * 16 + lg * 4);

    __syncthreads();

    // ---- A-fragments: A[t] rows h=t*16+l15, k(m) = lg*8 + e ----
    bf16x8 afrag[8];
    #pragma unroll
    for (int t = 0; t < 8; ++t) {
        const int h = t * 16 + l15;
        afrag[t] = *(const bf16x8*)(&w1_lds[h * LDS_STRIDE + lg * 8]);
    }
    // ---- per-lane layer-2 weights: h = t*16 + lg*4 + r ----
    float w2a[4][4], w2b[4][4];
    #pragma unroll
    for (int t = 0; t < 4; ++t)
        #pragma unroll
        for (int r = 0; r < 4; ++r) {
            const int h = t * 16 + lg * 4 + r;
            w2a[t][r] = w2_lds[h * 2 + 0];
            w2b[t][r] = w2_lds[h * 2 + 1];
        }

    // ---- main loop: this wave covers batches [wave*128, wave*128+128), 8 tiles of 16 ----
    const int bbase = wave * 128;
    // prefetch tile 0: B-frag lane l -> state[bbase+l15][d][lg*8 .. +8)
    const float* sp0 = st + ((size_t)(bbase + l15) * ND + d) * NM + lg * 8;
    f32x4 s0 = *(const f32x4*)sp0;
    f32x4 s1 = *(const f32x4*)(sp0 + 4);

    for (int bt = 0; bt < 8; ++bt) {
        f32x4 c0 = s0, c1 = s1;
        if (bt < 7) {   // prefetch next tile's state while we compute
            const float* sp = st + ((size_t)(bbase + (bt + 1) * 16 + l15) * ND + d) * NM + lg * 8;
            s0 = *(const f32x4*)sp;
            s1 = *(const f32x4*)(sp + 4);
        }
        // fp32 -> bf16 B-fragment (k = lg*8 + e)
        bf16x8 bfrag;
        #pragma unroll
        for (int j = 0; j < 4; ++j) {
            bfrag[j]     = (__bf16)c0[j];
            bfrag[j + 4] = (__bf16)c1[j];
        }
        // acc init = b1a (bias folded into C-in); D[i=h][j=batch]
        f32x4 acc[8];
        #pragma unroll
        for (int t = 0; t < 8; ++t) acc[t] = bias[t];
        #pragma unroll
        for (int t = 0; t < 8; ++t)
            acc[t] = __builtin_amdgcn_mfma_f32_16x16x32_bf16(afrag[t], bfrag, acc[t], 0, 0, 0);

        // epilogue: GLU pairs (h, h+64) = tiles (t, t+4), same reg r.
        // lane holds batch b = l15, h = t*16 + lg*4 + r
        float z0 = 0.0f, z1 = 0.0f;
        #pragma unroll
        for (int t = 0; t < 4; ++t)
            #pragma unroll
            for (int r = 0; r < 4; ++r) {
                const float ya = acc[t][r]     * rTa;
                const float yb = acc[t + 4][r] * rTa;
                const float g  = ya * sigmoid_fast(yb);
                z0 = fmaf(g, w2a[t][r], z0);
                z1 = fmaf(g, w2b[t][r], z1);
            }
        // reduce over the 4 lane-groups (h coverage) -> full 64-h dot per batch
        z0 += __shfl_xor(z0, 16);
        z0 += __shfl_xor(z0, 32);
        z1 += __shfl_xor(z1, 16);
        z1 += __shfl_xor(z1, 32);
        if (lg == 0) {
            const float za = (z0 + bb0) * rTb;
            const float zb = (z1 + bb1) * rTb;
            out[(size_t)(bbase + bt * 16 + l15) * ND + d] = za * sigmoid_fast(zb);
        }
    }
}

extern "C" void kernel_launch(void* const* d_in, const int* in_sizes, int n_in,
                              void* d_out, int out_size, void* d_ws, size_t ws_size,
                              hipStream_t stream) {
    const float* st  = (const float*)d_in[0];
    const float* w1a = (const float*)d_in[1];
    const float* b1a = (const float*)d_in[2];
    const float* Ta  = (const float*)d_in[3];
    const float* w1b = (const float*)d_in[4];
    const float* b1b = (const float*)d_in[5];
    const float* Tb  = (const float*)d_in[6];
    float* out = (float*)d_out;

    nlm_fused<<<dim3(ND), dim3(256), 0, stream>>>(st, w1a, b1a, Ta, w1b, b1b, Tb, out);
}

// Round 10
// 250.660 us; speedup vs baseline: 1.0421x; 1.0421x over previous
//
#include <hip/hip_runtime.h>
#include <hip/hip_bf16.h>

// NLM_7962869366897: fused per-feature GLU-MLP, two-phase.
// Phase A: transpose w1a [32][128][2048] f32 -> wsA [2048][128][32] bf16 (coalesced both sides)
//          transpose w1b [64][2][2048] f32  -> wsB [2048][128]     f32
// Phase B: per-d GEMM [512x32]@[32x128] via mfma_f32_16x16x32_bf16 (K=32),
//          weights read DIRECTLY from wsA (fragment layout == linear memory, no LDS),
//          GLU + layer2 [64x2] + GLU in fp32 VALU epilogue.

#define NB 512
#define ND 2048
#define NM 32
#define NH2 128  // 2H

typedef __bf16 bf16x8 __attribute__((ext_vector_type(8)));
typedef float f32x4 __attribute__((ext_vector_type(4)));
typedef float f32x2 __attribute__((ext_vector_type(2)));

#define WSA_BYTES ((size_t)ND * NH2 * NM * 2)   // 16.8 MB bf16

__device__ __forceinline__ float sigmoid_fast(float x) {
    return __builtin_amdgcn_rcpf(1.0f + __builtin_amdgcn_exp2f(-1.442695040888963f * x));
}

// ---------------- Phase A: weight transpose ----------------
// blocks 0..2047: w1a. block = (h-pair hp = bid&63, d-chunk dt = bid>>6).
//   reads 64 rows (p = m*128 + h0+hh) x 64 d, coalesced; writes [d][h0*32..+64) bf16, coalesced.
// blocks 2048..2175: w1b. block = 16-d chunk; reads 128 rows x 16 d; writes [d][128] f32.
__global__ __launch_bounds__(256) void transpose_w(const float* __restrict__ w1a,
                                                   const float* __restrict__ w1b,
                                                   __bf16* __restrict__ wsA,
                                                   float* __restrict__ wsB) {
    __shared__ float tile[64 * 65];  // also covers 128*17 for the w1b path
    const int tid = threadIdx.x;
    if (blockIdx.x < 2048) {
        const int h0 = (blockIdx.x & 63) * 2;
        const int d0 = (blockIdx.x >> 6) * 64;
        const int dc = tid & 63, wv = tid >> 6;
        #pragma unroll
        for (int k = 0; k < 16; ++k) {
            const int rr = wv + 4 * k;          // 0..63
            const int m = rr >> 1, hh = rr & 1;
            tile[rr * 65 + dc] = w1a[(size_t)(m * 128 + h0 + hh) * ND + d0 + dc];
        }
        __syncthreads();
        const int dloc = tid >> 2, seg = tid & 3;
        bf16x8 u0, u1;
        #pragma unroll
        for (int i = 0; i < 8; ++i) {
            const int q0 = seg * 16 + i;        // q' = hh*32 + m
            u0[i] = (__bf16)tile[((q0 & 31) * 2 + (q0 >> 5)) * 65 + dloc];
            const int q1 = seg * 16 + 8 + i;
            u1[i] = (__bf16)tile[((q1 & 31) * 2 + (q1 >> 5)) * 65 + dloc];
        }
        __bf16* dst = wsA + (size_t)(d0 + dloc) * (NH2 * NM) + h0 * 32 + seg * 16;
        *(bf16x8*)dst = u0;
        *(bf16x8*)(dst + 8) = u1;
    } else {
        const int d0 = (blockIdx.x - 2048) * 16;
        const int dcol = tid & 15, pr = tid >> 4;
        #pragma unroll
        for (int k = 0; k < 8; ++k) {
            const int p = pr + 16 * k;          // 0..127
            tile[p * 17 + dcol] = w1b[(size_t)p * ND + d0 + dcol];
        }
        __syncthreads();
        const int dloc = tid >> 4, j = tid & 15;
        #pragma unroll
        for (int i = 0; i < 8; ++i) {
            const int row = j * 8 + i;
            wsB[(size_t)(d0 + dloc) * 128 + j * 8 + i] = tile[row * 17 + dloc];
        }
    }
}

// ---------------- Phase B: fused compute ----------------
__global__ __launch_bounds__(256) void nlm_fused(
    const float*  __restrict__ st,   // [B, D, M]
    const __bf16* __restrict__ wsA,  // [D][128][32] bf16
    const float*  __restrict__ b1a,  // [1, D, 2H]
    const float*  __restrict__ Ta,
    const float*  __restrict__ wsB,  // [D][128] f32 (h*2+c)
    const float*  __restrict__ b1b,  // [1, D, 2]
    const float*  __restrict__ Tb,
    float*        __restrict__ out)  // [B, D]
{
    const int d    = blockIdx.x;
    const int tid  = threadIdx.x;
    const int wave = tid >> 6;
    const int lane = tid & 63;
    const int l15  = lane & 15;
    const int lg   = lane >> 4;     // 0..3

    // A-fragments straight from global: fragment (h=t*16+l15, m=lg*8..+8) is
    // linear in wsA -> 16 fully-used 64B lines per load instr; L1-shared by all waves.
    const __bf16* wA = wsA + (size_t)d * (NH2 * NM);
    bf16x8 afrag[8];
    #pragma unroll
    for (int t = 0; t < 8; ++t)
        afrag[t] = *(const bf16x8*)(wA + (t * 16 + l15) * 32 + lg * 8);

    // bias as MFMA C-init: bias[t][r] = b1a[d][t*16+lg*4+r]
    f32x4 bias[8];
    #pragma unroll
    for (int t = 0; t < 8; ++t)
        bias[t] = *(const f32x4*)(b1a + (size_t)d * 128 + t * 16 + lg * 4);

    // layer-2 weights, contiguous pairs (h*2, h*2+1)
    const float* w2d = wsB + (size_t)d * 128;
    float w2a[4][4], w2b[4][4];
    #pragma unroll
    for (int t = 0; t < 4; ++t)
        #pragma unroll
        for (int r = 0; r < 4; ++r) {
            const int h = t * 16 + lg * 4 + r;
            f32x2 p = *(const f32x2*)(w2d + h * 2);
            w2a[t][r] = p[0];
            w2b[t][r] = p[1];
        }

    const float rTa = 1.0f / Ta[0];
    const float rTb = 1.0f / Tb[0];
    const float bb0 = b1b[d * 2 + 0];
    const float bb1 = b1b[d * 2 + 1];

    // main loop: wave covers batches [wave*128, +128), 8 tiles of 16
    const int bbase = wave * 128;
    const float* sp0 = st + ((size_t)(bbase + l15) * ND + d) * NM + lg * 8;
    f32x4 s0 = *(const f32x4*)sp0;
    f32x4 s1 = *(const f32x4*)(sp0 + 4);

    for (int bt = 0; bt < 8; ++bt) {
        f32x4 c0 = s0, c1 = s1;
        if (bt < 7) {
            const float* sp = st + ((size_t)(bbase + (bt + 1) * 16 + l15) * ND + d) * NM + lg * 8;
            s0 = *(const f32x4*)sp;
            s1 = *(const f32x4*)(sp + 4);
        }
        bf16x8 bfrag;
        #pragma unroll
        for (int j = 0; j < 4; ++j) {
            bfrag[j]     = (__bf16)c0[j];
            bfrag[j + 4] = (__bf16)c1[j];
        }
        f32x4 acc[8];
        #pragma unroll
        for (int t = 0; t < 8; ++t) acc[t] = bias[t];
        #pragma unroll
        for (int t = 0; t < 8; ++t)
            acc[t] = __builtin_amdgcn_mfma_f32_16x16x32_bf16(afrag[t], bfrag, acc[t], 0, 0, 0);

        // GLU pairs (h, h+64) = tiles (t, t+4), same reg r; lane holds batch l15.
        float z0 = 0.0f, z1 = 0.0f;
        #pragma unroll
        for (int t = 0; t < 4; ++t)
            #pragma unroll
            for (int r = 0; r < 4; ++r) {
                const float ya = acc[t][r]     * rTa;
                const float yb = acc[t + 4][r] * rTa;
                const float g  = ya * sigmoid_fast(yb);
                z0 = fmaf(g, w2a[t][r], z0);
                z1 = fmaf(g, w2b[t][r], z1);
            }
        z0 += __shfl_xor(z0, 16);
        z0 += __shfl_xor(z0, 32);
        z1 += __shfl_xor(z1, 16);
        z1 += __shfl_xor(z1, 32);
        if (lg == 0) {
            const float za = (z0 + bb0) * rTb;
            const float zb = (z1 + bb1) * rTb;
            out[(size_t)(bbase + bt * 16 + l15) * ND + d] = za * sigmoid_fast(zb);
        }
    }
}

extern "C" void kernel_launch(void* const* d_in, const int* in_sizes, int n_in,
                              void* d_out, int out_size, void* d_ws, size_t ws_size,
                              hipStream_t stream) {
    const float* st  = (const float*)d_in[0];
    const float* w1a = (const float*)d_in[1];
    const float* b1a = (const float*)d_in[2];
    const float* Ta  = (const float*)d_in[3];
    const float* w1b = (const float*)d_in[4];
    const float* b1b = (const float*)d_in[5];
    const float* Tb  = (const float*)d_in[6];
    float* out = (float*)d_out;

    __bf16* wsA = (__bf16*)d_ws;
    float*  wsB = (float*)((char*)d_ws + WSA_BYTES);

    transpose_w<<<dim3(2048 + 128), dim3(256), 0, stream>>>(w1a, w1b, wsA, wsB);
    nlm_fused<<<dim3(ND), dim3(256), 0, stream>>>(st, wsA, b1a, Ta, wsB, b1b, Tb, out);
}